// Round 3
// baseline (352.023 us; speedup 1.0000x reference)
//
#include <hip/hip_runtime.h>

// Problem constants
#define BS1 32
#define BS2 128
#define NEC 64
#define QD  256   // Q_DIM
#define MD  256   // MLP_DIM (== MEM_DIM)

// att[b,e] = softmax over e of dot(criteria[b,e,:], W_align[:QD])
// (softmax is shift-invariant: logit_e[p] + b_align cancel over axis e)
__global__ __launch_bounds__(64)
void att_kernel(const float* __restrict__ crit,
                const float* __restrict__ w_align,
                float* __restrict__ att) {
    __shared__ float wa[QD];
    int b = blockIdx.x, e = threadIdx.x;
    for (int i = e; i < QD; i += 64) wa[i] = w_align[i];
    __syncthreads();
    const float* row = crit + (b * NEC + e) * QD;
    float acc = 0.f;
    for (int k = 0; k < QD; k += 4) {
        float4 u = *(const float4*)(row + k);
        acc = fmaf(u.x, wa[k + 0], acc);
        acc = fmaf(u.y, wa[k + 1], acc);
        acc = fmaf(u.z, wa[k + 2], acc);
        acc = fmaf(u.w, wa[k + 3], acc);
    }
    // wave64 softmax across the 64 e-lanes
    float m = acc;
    #pragma unroll
    for (int off = 32; off; off >>= 1) m = fmaxf(m, __shfl_xor(m, off));
    float ex = __expf(acc - m);
    float s = ex;
    #pragma unroll
    for (int off = 32; off; off >>= 1) s += __shfl_xor(s, off);
    att[b * NEC + e] = ex / s;
}

// out[m, 0:256] = A[m, 0:256] @ B[0:256, 0:256], all fp32.
// 8 rows per block; thread (r = tid>>5, c = (tid&31)*8) owns 8 cols of row r.
__global__ __launch_bounds__(256)
void gemm_rows8(const float* __restrict__ A,
                const float* __restrict__ B,
                float* __restrict__ out) {
    __shared__ float As[8 * QD];   // 8 KB A tile
    int tid = threadIdx.x;
    int m0 = blockIdx.x * 8;
    {
        const float* src = A + m0 * QD + tid * 8;
        float4 a0 = *(const float4*)src;
        float4 a1 = *(const float4*)(src + 4);
        *(float4*)&As[tid * 8]     = a0;
        *(float4*)&As[tid * 8 + 4] = a1;
    }
    __syncthreads();
    int r = tid >> 5;           // r in [0,8) across block
    int c = (tid & 31) * 8;
    float acc[8] = {0.f,0.f,0.f,0.f,0.f,0.f,0.f,0.f};
    #pragma unroll 4
    for (int k = 0; k < QD; ++k) {
        float a = As[r * QD + k];
        const float* bp = B + k * MD + c;
        float4 b0 = *(const float4*)bp;
        float4 b1 = *(const float4*)(bp + 4);
        acc[0] = fmaf(a, b0.x, acc[0]);
        acc[1] = fmaf(a, b0.y, acc[1]);
        acc[2] = fmaf(a, b0.z, acc[2]);
        acc[3] = fmaf(a, b0.w, acc[3]);
        acc[4] = fmaf(a, b1.x, acc[4]);
        acc[5] = fmaf(a, b1.y, acc[5]);
        acc[6] = fmaf(a, b1.z, acc[6]);
        acc[7] = fmaf(a, b1.w, acc[7]);
    }
    float* o = out + (m0 + r) * MD + c;
    *(float4*)o       = make_float4(acc[0], acc[1], acc[2], acc[3]);
    *(float4*)(o + 4) = make_float4(acc[4], acc[5], acc[6], acc[7]);
}

// h[b,p,e,d] = att[b,e] * (proj_c[b,e,d] + proj_e[p,d]) + b_mlp[d], fp32 out.
// One block per (b,p); 8 passes x 256 threads x 8 elems = 64 e x 256 d.
__global__ __launch_bounds__(256)
void final_kernel(const float* __restrict__ att,
                  const float* __restrict__ proj_c,
                  const float* __restrict__ proj_e,
                  const float* __restrict__ b_mlp,
                  float*       __restrict__ out) {
    __shared__ float pe[MD], bm[MD], attb[NEC];
    int tid = threadIdx.x;
    int bp  = blockIdx.x;
    int b = bp >> 7, p = bp & 127;
    pe[tid] = proj_e[p * MD + tid];
    bm[tid] = b_mlp[tid];
    if (tid < NEC) attb[tid] = att[b * NEC + tid];
    __syncthreads();
    const float* pc_base = proj_c + b * NEC * MD;
    float* out_base = out + (size_t)bp * (NEC * MD);
    #pragma unroll
    for (int pass = 0; pass < 8; ++pass) {
        int idx = pass * 256 + tid;
        int e = idx >> 5;          // [0,64)
        int d = (idx & 31) * 8;    // [0,256) step 8
        float a = attb[e];         // 2 addrs/wave: free LDS broadcast
        const float* pc = pc_base + e * MD + d;
        float4 c0 = *(const float4*)pc;
        float4 c1 = *(const float4*)(pc + 4);
        float4 e0 = *(const float4*)&pe[d];
        float4 e1 = *(const float4*)&pe[d + 4];
        float4 m0 = *(const float4*)&bm[d];
        float4 m1 = *(const float4*)&bm[d + 4];
        float4 r0, r1;
        r0.x = fmaf(a, c0.x + e0.x, m0.x);
        r0.y = fmaf(a, c0.y + e0.y, m0.y);
        r0.z = fmaf(a, c0.z + e0.z, m0.z);
        r0.w = fmaf(a, c0.w + e0.w, m0.w);
        r1.x = fmaf(a, c1.x + e1.x, m1.x);
        r1.y = fmaf(a, c1.y + e1.y, m1.y);
        r1.z = fmaf(a, c1.z + e1.z, m1.z);
        r1.w = fmaf(a, c1.w + e1.w, m1.w);
        float* o = out_base + (size_t)idx * 8;   // wave-contiguous 2 KiB stores
        *(float4*)o       = r0;
        *(float4*)(o + 4) = r1;
    }
}

extern "C" void kernel_launch(void* const* d_in, const int* in_sizes, int n_in,
                              void* d_out, int out_size, void* d_ws, size_t ws_size,
                              hipStream_t stream) {
    // setup_inputs order: ehr_vector, criteria, ec_mask, W_align, b_align, W_mlp, b_mlp
    const float* ehr     = (const float*)d_in[0];   // (128, 256) fp32
    const float* crit    = (const float*)d_in[1];   // (32, 64, 256) fp32
    // d_in[2] ec_mask: all-ones, unused by reference
    const float* w_align = (const float*)d_in[3];   // (512,) -> use [:256]
    // d_in[4] b_align: cancels in softmax
    const float* w_mlp   = (const float*)d_in[5];   // (512, 256) row-major fp32
    const float* b_mlp   = (const float*)d_in[6];   // (256,)
    float* out = (float*)d_out;                      // (32,128,64,256) fp32

    // workspace layout (fp32): att[2048] | proj_c[2048*256] | proj_e[128*256]
    float* att    = (float*)d_ws;
    float* proj_c = att + BS1 * NEC;
    float* proj_e = proj_c + BS1 * NEC * MD;

    att_kernel<<<BS1, 64, 0, stream>>>(crit, w_align, att);
    gemm_rows8<<<(BS1 * NEC) / 8, 256, 0, stream>>>(crit, w_mlp, proj_c);
    gemm_rows8<<<BS2 / 8, 256, 0, stream>>>(ehr, w_mlp + QD * MD, proj_e);
    final_kernel<<<BS1 * BS2, 256, 0, stream>>>(att, proj_c, proj_e, b_mlp, out);
}